// Round 8
// baseline (3485.988 us; speedup 1.0000x reference)
//
#include <hip/hip_runtime.h>

typedef __attribute__((ext_vector_type(8))) short bf16x8;
typedef __attribute__((ext_vector_type(4))) float f32x4;
typedef unsigned short ushort_t;
typedef unsigned int uint32;
typedef unsigned long long u64;

#define DEVI __device__ __forceinline__

static constexpr int Bn = 128, Sn = 256, In = 512, Hn = 512;
static constexpr int G3 = 3 * Hn;                 // 1536

// ws layout (bytes)
static constexpr size_t GI_OFF    = 0;                              // bf16 [B*S][1536]
static constexpr size_t GI_BYTES  = (size_t)Bn * Sn * G3 * 2;       // 100,663,296
static constexpr size_t WIH_OFF   = GI_OFF + GI_BYTES;              // bf16 [1536][512]
static constexpr size_t WIH_BYTES = (size_t)G3 * In * 2;            // 1,572,864
static constexpr size_t HBUFF_OFF = WIH_OFF + WIH_BYTES;            // fast-mode h [2][B][H]
static constexpr size_t HBUFM_OFF = HBUFF_OFF + 262144;             // mall-mode h [2][B][H]
static constexpr size_t FLAGF_OFF = HBUFM_OFF + 262144;             // fast flags (32x128B)
static constexpr size_t FLAGM_OFF = FLAGF_OFF + 4096;               // mall flags
static constexpr size_t VERD_OFF  = FLAGM_OFF + 4096;               // verdicts (32x128B)
static constexpr size_t ARR_OFF   = VERD_OFF + 4096;                // 256 u32 rendezvous

DEVI ushort_t f2bf(float f) {
  uint32 u = __builtin_bit_cast(uint32, f);
  u += 0x7FFFu + ((u >> 16) & 1u);
  return (ushort_t)(u >> 16);
}
DEVI float bf2f(ushort_t h) {
  uint32 u = ((uint32)h) << 16;
  return __builtin_bit_cast(float, u);
}
DEVI float sigmoid_f(float x) { return 1.0f / (1.0f + __expf(-x)); }
DEVI float tanh_f(float x)    { return 2.0f / (1.0f + __expf(-2.0f * x)) - 1.0f; }
DEVI void l1_inv() { asm volatile("buffer_inv sc0" ::: "memory"); }

// --- kernel 0: convert W_ih f32 -> bf16 ---------------------------------
__global__ void k_cvt_wih(const float* __restrict__ wih, ushort_t* __restrict__ out) {
  int i = blockIdx.x * blockDim.x + threadIdx.x;
  const float4 v = ((const float4*)wih)[i];
  ushort4 o;
  o.x = f2bf(v.x); o.y = f2bf(v.y); o.z = f2bf(v.z); o.w = f2bf(v.w);
  ((ushort4*)out)[i] = o;
}

// --- kernel 1: gi = x @ W_ih^T + b_ih  (bf16 out) -----------------------
__launch_bounds__(512)
__global__ void k_gi(const float* __restrict__ x, const ushort_t* __restrict__ wihb,
                     const float* __restrict__ b_ih, ushort_t* __restrict__ gi) {
  extern __shared__ ushort_t apan[];   // [128][520] bf16
  const int tid = threadIdx.x;
  const int bm  = blockIdx.x;
#pragma unroll
  for (int it = 0; it < 32; ++it) {
    int fidx = it * 512 + tid;
    int row = fidx >> 7, c4 = fidx & 127;
    const float4 v = *(const float4*)(x + ((size_t)(bm * 128 + row) << 9) + (c4 << 2));
    ushort4 o;
    o.x = f2bf(v.x); o.y = f2bf(v.y); o.z = f2bf(v.z); o.w = f2bf(v.w);
    *(ushort4*)(&apan[row * 520 + (c4 << 2)]) = o;
  }
  __syncthreads();
  const int lane = tid & 63, wid = tid >> 6;
  const int l15 = lane & 15, hi = lane >> 4;
  const int arow = wid * 16 + l15;
  for (int nt = 0; nt < 12; ++nt) {
    const int n0 = nt * 128;
    f32x4 acc[8] = {};
#pragma unroll
    for (int ks = 0; ks < 16; ++ks) {
      bf16x8 a = *(const bf16x8*)(&apan[arow * 520 + ks * 32 + hi * 8]);
#pragma unroll
      for (int j = 0; j < 8; ++j) {
        const ushort_t* wp = wihb + ((size_t)(n0 + j * 16 + l15) << 9) + ks * 32 + hi * 8;
        bf16x8 b = *(const bf16x8*)wp;
        acc[j] = __builtin_amdgcn_mfma_f32_16x16x32_bf16(a, b, acc[j], 0, 0, 0);
      }
    }
#pragma unroll
    for (int j = 0; j < 8; ++j) {
      const int n = n0 + j * 16 + l15;
      const float bias = b_ih[n];
#pragma unroll
      for (int r = 0; r < 4; ++r) {
        int m = bm * 128 + wid * 16 + hi * 4 + r;
        gi[(size_t)m * 1536 + n] = f2bf(acc[j][r] + bias);
      }
    }
  }
}

// --- kernel 2: dual-mode persistent masked-GRU scan ----------------------
// FAST mode: intra-XCD L2 exchange (sc0 stores + l1_inv/sc0 loads), probed
// at init. If ANY rank misses the fast flags, all ranks agree (via MALL
// verdict exchange) to fall back to the round-5 MALL protocol (agent-scope
// atomics) on SEPARATE buffers. Self-validating, no regression risk.
__launch_bounds__(512)
__global__ void k_scan3(const float* __restrict__ hx, const float* __restrict__ mask,
                        const float* __restrict__ whh, const float* __restrict__ bhh,
                        const ushort_t* __restrict__ gi,
                        u64* __restrict__ hbufF, u64* __restrict__ hbufM,
                        uint32* __restrict__ flagF, uint32* __restrict__ flagM,
                        uint32* __restrict__ verd, uint32* __restrict__ arr,
                        float* __restrict__ out) {
  __shared__ ushort_t Wl[48 * 520];
  __shared__ ushort_t hpack[128 * 16];
  __shared__ unsigned char xl[256];
  __shared__ int meta[2];
  __shared__ int s_abort;
  const int tid = threadIdx.x;
  const int bid = blockIdx.x;

  uint32 xcd;
  asm("s_getreg_b32 %0, hwreg(HW_REG_XCC_ID)" : "=s"(xcd));
  if (tid == 0) {
    s_abort = 0;
    __hip_atomic_store(&arr[bid], 0x80u | xcd, __ATOMIC_RELAXED, __HIP_MEMORY_SCOPE_AGENT);
  }
  const int widx = tid & 255;
  uint32 aval = 0;
  int ok = 0;
  for (int spin = 0; spin < 20000 && !ok; ++spin) {
    aval = __hip_atomic_load(&arr[widx], __ATOMIC_RELAXED, __HIP_MEMORY_SCOPE_AGENT);
    ok = __syncthreads_and((int)(aval & 0x80u));
    if (!ok) __builtin_amdgcn_s_sleep(8);
  }
  if (!ok) return;
  xl[widx] = (unsigned char)(aval & 0x7fu);
  __syncthreads();
  if (tid == 0) {
    int cnt[16] = {};
    int rank = 0;
    for (int j = 0; j < 256; ++j) {
      int x = xl[j] & 15;
      cnt[x]++;
      if (j < bid && x == (int)(xcd & 15)) rank++;
    }
    int wr = -1;
    for (int x = 0; x < 16; ++x) if (cnt[x] >= 32) { wr = x; break; }
    meta[0] = rank; meta[1] = wr;
  }
  __syncthreads();
  const int rank = meta[0], wr = meta[1];
  if (wr < 0 || (int)(xcd & 15) != wr || rank >= 32) return;
  const int c0 = rank * 16;

  for (int r = 0; r < 48; ++r) {
    int g = r >> 4, j = r & 15;
    Wl[r * 520 + tid] = f2bf(whh[(size_t)(g * 512 + c0 + j) * 512 + tid]);
  }

  const int lane = tid & 63, wid = tid >> 6;
  const int l15 = lane & 15, hi = lane >> 4;
  const int arow = wid * 16 + l15;

  float hreg[4];
#pragma unroll
  for (int r = 0; r < 4; ++r) {
    int b = wid * 16 + hi * 4 + r;
    hreg[r] = hx[b * 512 + c0 + l15] * mask[b * 256];
    hpack[b * 16 + l15] = f2bf(hreg[r]);
  }
  __syncthreads();

  // ---- FAST-mode probe: publish h0 via sc0 stores, flag, short poll ----
  {
    int b = tid >> 2, q = tid & 3;
    u64 v = *(const u64*)(&hpack[b * 16 + q * 4]);
    u64* dst = hbufF + (size_t)b * 128 + (c0 >> 2) + q;
    asm volatile("global_store_dwordx2 %0, %1, off sc0" :: "v"(dst), "v"(v) : "memory");
  }
  __syncthreads();                       // drain vmcnt
  if (tid == 0) {
    uint32 one = 1;
    asm volatile("global_store_dword %0, %1, off sc0" :: "v"(flagF + rank * 32), "v"(one) : "memory");
  }
  int got = 0;
  if (tid < 32) {
    for (int spin = 0; spin < 5000; ++spin) {     // ~1ms probe
      l1_inv();
      uint32 f;
      asm volatile("global_load_dword %0, %1, off sc0\n\ts_waitcnt vmcnt(0)"
                   : "=v"(f) : "v"(flagF + tid * 32) : "memory");
      if (f >= 1u) { got = 1; break; }
      __builtin_amdgcn_s_sleep(1);
    }
  }
  int fastmode = __syncthreads_and((tid < 32) ? got : 1);
  // ---- verdict agreement via MALL (always correct) ----
  if (tid == 0)
    __hip_atomic_store(verd + rank * 32, fastmode ? 1u : 2u, __ATOMIC_RELAXED, __HIP_MEMORY_SCOPE_AGENT);
  uint32 pv = 0;
  if (tid < 32) {
    for (int spin = 0; spin < 50000; ++spin) {
      pv = __hip_atomic_load(verd + tid * 32, __ATOMIC_RELAXED, __HIP_MEMORY_SCOPE_AGENT);
      if (pv) break;
      __builtin_amdgcn_s_sleep(1);
    }
  }
  int present = __syncthreads_and((tid < 32) ? (pv != 0) : 1);
  if (!present) return;                  // fail fast, visible
  fastmode = __syncthreads_and((tid < 32) ? (pv == 1u) : 1);

  if (!fastmode) {
    // ---- MALL fallback: republish h0, round-5 protocol, separate buffers ----
    {
      int b = tid >> 2, q = tid & 3;
      u64 v = *(const u64*)(&hpack[b * 16 + q * 4]);
      __hip_atomic_store(hbufM + (size_t)b * 128 + (c0 >> 2) + q, v,
                         __ATOMIC_RELAXED, __HIP_MEMORY_SCOPE_AGENT);
    }
    __syncthreads();
    if (tid == 0)
      __hip_atomic_store(flagM + rank * 32, 1u, __ATOMIC_RELAXED, __HIP_MEMORY_SCOPE_AGENT);
    int g2 = 0;
    if (tid < 32) {
      for (int spin = 0; spin < 50000; ++spin) {
        if (__hip_atomic_load(flagM + tid * 32, __ATOMIC_RELAXED, __HIP_MEMORY_SCOPE_AGENT) >= 1u) { g2 = 1; break; }
        __builtin_amdgcn_s_sleep(1);
      }
      if (!g2) s_abort = 1;
    }
    __syncthreads();
  }

  ushort_t pg0[4], pg1[4], pg2[4];
  float pmk[4];
#pragma unroll
  for (int r = 0; r < 4; ++r) {
    int b = wid * 16 + hi * 4 + r;
    size_t gb = (size_t)(b * 256 + 0) * 1536 + c0 + l15;
    pg0[r] = gi[gb];
    pg1[r] = gi[gb + 512];
    pg2[r] = gi[gb + 1024];
    pmk[r] = mask[b * 256 + 1];
  }

  const float bhh_r = bhh[c0 + l15];
  const float bhh_z = bhh[512 + c0 + l15];
  const float bhh_n = bhh[1024 + c0 + l15];
  int p = 0;

  for (int t = 0; t < 256; ++t) {
    u64 ha[32];
    if (fastmode) {
      const u64* hb = hbufF + (size_t)p * 16384;
      l1_inv();
#pragma unroll
      for (int ks = 0; ks < 16; ++ks) {
        const u64* ap = hb + (size_t)arow * 128 + ks * 8 + hi * 2;
        asm volatile("global_load_dwordx2 %0, %1, off sc0" : "=v"(ha[2 * ks]) : "v"(ap));
        asm volatile("global_load_dwordx2 %0, %1, off sc0" : "=v"(ha[2 * ks + 1]) : "v"(ap + 1));
      }
      asm volatile("s_waitcnt vmcnt(0)" ::: "memory");
      __builtin_amdgcn_sched_barrier(0);
    } else {
      const u64* hb = hbufM + (size_t)p * 16384;
#pragma unroll
      for (int ks = 0; ks < 16; ++ks) {
        size_t base = (size_t)arow * 128 + ks * 8 + hi * 2;
        ha[2 * ks]     = __hip_atomic_load(hb + base, __ATOMIC_RELAXED, __HIP_MEMORY_SCOPE_AGENT);
        ha[2 * ks + 1] = __hip_atomic_load(hb + base + 1, __ATOMIC_RELAXED, __HIP_MEMORY_SCOPE_AGENT);
      }
      __builtin_amdgcn_sched_barrier(0);
    }

    f32x4 acc[3] = {};
#pragma unroll
    for (int ks = 0; ks < 16; ++ks) {
      union { u64 q[2]; bf16x8 v; } ua;
      ua.q[0] = ha[2 * ks]; ua.q[1] = ha[2 * ks + 1];
#pragma unroll
      for (int g = 0; g < 3; ++g) {
        bf16x8 w = *(const bf16x8*)(&Wl[(g * 16 + l15) * 520 + ks * 32 + hi * 8]);
        acc[g] = __builtin_amdgcn_mfma_f32_16x16x32_bf16(ua.v, w, acc[g], 0, 0, 0);
      }
    }

#pragma unroll
    for (int r = 0; r < 4; ++r) {
      int b = wid * 16 + hi * 4 + r;
      float rg = sigmoid_f(bf2f(pg0[r]) + acc[0][r] + bhh_r);
      float zg = sigmoid_f(bf2f(pg1[r]) + acc[1][r] + bhh_z);
      float ng = tanh_f(bf2f(pg2[r]) + rg * (acc[2][r] + bhh_n));
      float hn = (1.0f - zg) * ng + zg * hreg[r];
      out[(size_t)(b * 256 + t) * 512 + c0 + l15] = hn;
      if (t == 255) {
        out[(size_t)(128 * 256) * 512 + b * 512 + c0 + l15] = hn;
      } else {
        float hm = hn * pmk[r];
        hreg[r] = hm;
        hpack[b * 16 + l15] = f2bf(hm);
      }
    }

    if (t < 255) {
      __syncthreads();                 // hpack complete
      {
        int b = tid >> 2, q = tid & 3;
        u64 v = *(const u64*)(&hpack[b * 16 + q * 4]);
        size_t off = (size_t)(p ^ 1) * 16384 + (size_t)b * 128 + (c0 >> 2) + q;
        if (fastmode) {
          u64* dst = hbufF + off;
          asm volatile("global_store_dwordx2 %0, %1, off sc0" :: "v"(dst), "v"(v) : "memory");
        } else {
          __hip_atomic_store(hbufM + off, v, __ATOMIC_RELAXED, __HIP_MEMORY_SCOPE_AGENT);
        }
      }
      __syncthreads();                 // drain vmcnt: h(t+1) at exchange point
      if (!s_abort && tid == 0) {
        uint32 want = (uint32)(t + 2);
        if (fastmode) {
          asm volatile("global_store_dword %0, %1, off sc0" :: "v"(flagF + rank * 32), "v"(want) : "memory");
        } else {
          __hip_atomic_store(flagM + rank * 32, want, __ATOMIC_RELAXED, __HIP_MEMORY_SCOPE_AGENT);
        }
      }
      {
        int tn = t + 1;
#pragma unroll
        for (int r = 0; r < 4; ++r) {
          int b = wid * 16 + hi * 4 + r;
          size_t gb = (size_t)(b * 256 + tn) * 1536 + c0 + l15;
          pg0[r] = gi[gb];
          pg1[r] = gi[gb + 512];
          pg2[r] = gi[gb + 1024];
          pmk[r] = (tn < 255) ? mask[b * 256 + tn + 1] : 0.0f;
        }
      }
      if (!s_abort && tid < 32) {
        uint32 want = (uint32)(t + 2);
        int g3 = 0;
        for (int spin = 0; spin < 50000; ++spin) {
          uint32 f;
          if (fastmode) {
            l1_inv();
            asm volatile("global_load_dword %0, %1, off sc0\n\ts_waitcnt vmcnt(0)"
                         : "=v"(f) : "v"(flagF + tid * 32) : "memory");
          } else {
            f = __hip_atomic_load(flagM + tid * 32, __ATOMIC_RELAXED, __HIP_MEMORY_SCOPE_AGENT);
          }
          if (f >= want) { g3 = 1; break; }
          __builtin_amdgcn_s_sleep(1);
        }
        if (!g3) s_abort = 1;          // latch: fail fast, never wedge
      }
      __syncthreads();
      p ^= 1;
    }
  }
}

extern "C" void kernel_launch(void* const* d_in, const int* in_sizes, int n_in,
                              void* d_out, int out_size, void* d_ws, size_t ws_size,
                              hipStream_t stream) {
  (void)in_sizes; (void)n_in; (void)out_size; (void)ws_size;
  const float* x    = (const float*)d_in[0];
  const float* hx   = (const float*)d_in[1];
  const float* mask = (const float*)d_in[2];
  const float* Wih  = (const float*)d_in[3];
  const float* Whh  = (const float*)d_in[4];
  const float* bih  = (const float*)d_in[5];
  const float* bhh  = (const float*)d_in[6];
  float* out = (float*)d_out;
  char* ws = (char*)d_ws;
  ushort_t* gi    = (ushort_t*)(ws + GI_OFF);
  ushort_t* wihb  = (ushort_t*)(ws + WIH_OFF);
  u64*      hbufF = (u64*)(ws + HBUFF_OFF);
  u64*      hbufM = (u64*)(ws + HBUFM_OFF);
  uint32*   flagF = (uint32*)(ws + FLAGF_OFF);
  uint32*   flagM = (uint32*)(ws + FLAGM_OFF);
  uint32*   verd  = (uint32*)(ws + VERD_OFF);
  uint32*   arr   = (uint32*)(ws + ARR_OFF);

  hipMemsetAsync(ws + FLAGF_OFF, 0, 4096 * 3 + 1024, stream); // flags+verd+arr
  k_cvt_wih<<<768, 256, 0, stream>>>(Wih, wihb);
  k_gi<<<256, 512, 128 * 520 * 2, stream>>>(x, wihb, bih, gi);
  k_scan3<<<256, 512, 0, stream>>>(hx, mask, Whh, bhh, gi, hbufF, hbufM,
                                   flagF, flagM, verd, arr, out);
}